// Round 1
// baseline (5221.441 us; speedup 1.0000x reference)
//
#include <hip/hip_runtime.h>
#include <cstdint>

#define HW 131072        // H*W
#define CHW 8388608      // 64*HW
#define S_ELEMS 16777216 // B*C*H*W

// ---------------- BN stats: one block per channel ----------------
__global__ __launch_bounds__(256) void bn_stats_k(const float* __restrict__ x,
                                                  float* __restrict__ mu,
                                                  float* __restrict__ rstd) {
  int c = blockIdx.x;
  float s1 = 0.f, s2 = 0.f;
  for (int bb = 0; bb < 2; ++bb) {
    const float* p = x + ((size_t)(bb * 64 + c)) * HW;
    for (int i = threadIdx.x; i < HW; i += 256) {
      float v = p[i];
      s1 += v;
      s2 += v * v;
    }
  }
  for (int m = 32; m; m >>= 1) {
    s1 += __shfl_xor(s1, m, 64);
    s2 += __shfl_xor(s2, m, 64);
  }
  __shared__ float r1[4], r2[4];
  int wv = threadIdx.x >> 6;
  if ((threadIdx.x & 63) == 0) { r1[wv] = s1; r2[wv] = s2; }
  __syncthreads();
  if (threadIdx.x == 0) {
    float t1 = r1[0] + r1[1] + r1[2] + r1[3];
    float t2 = r2[0] + r2[1] + r2[2] + r2[3];
    float m = t1 / 262144.f;
    float var = t2 / 262144.f - m * m;
    mu[c] = m;
    rstd[c] = rsqrtf(var + 1e-5f);
  }
}

// ---------------- BN apply ----------------
__global__ __launch_bounds__(256) void bn_apply_k(const float* __restrict__ x,
                                                  float* __restrict__ y,
                                                  const float* __restrict__ mu,
                                                  const float* __restrict__ rstd,
                                                  const float* __restrict__ gamma,
                                                  const float* __restrict__ beta) {
  size_t i = (size_t)blockIdx.x * 256 + threadIdx.x;
  int c = (int)((i >> 17) & 63);
  y[i] = (x[i] - mu[c]) * rstd[c] * gamma[c] + beta[c];
}

// ---------------- grouped 3x3 conv (pad=1), optional leaky / residual ----------------
template <bool LEAKY, bool RES>
__global__ __launch_bounds__(256) void conv3x3g_k(const float* __restrict__ in,
                                                  const float* __restrict__ wgt,
                                                  const float* __restrict__ bias,
                                                  const float* __restrict__ res,
                                                  float* __restrict__ out) {
  __shared__ float wsm[144];
  int idx = blockIdx.x * 256 + threadIdx.x;
  int w = idx & 511;
  int h = (idx >> 9) & 255;
  int o = (idx >> 17) & 63;  // uniform within block
  int b = idx >> 23;
  if (threadIdx.x < 144) wsm[threadIdx.x] = wgt[o * 144 + threadIdx.x];
  __syncthreads();
  int g = o >> 4;
  const float* inb = in + ((size_t)(b * 64 + g * 16)) * HW;
  float acc = bias[o];
  for (int ci = 0; ci < 16; ++ci) {
    const float* ch = inb + (size_t)ci * HW;
    const float* wr0 = wsm + ci * 9;
    for (int kh = 0; kh < 3; ++kh) {
      int hh = h + kh - 1;
      if (hh < 0 || hh > 255) continue;
      const float* row = ch + hh * 512;
      const float* wr = wr0 + kh * 3;
      if (w >= 1 && w <= 510) {
        acc += wr[0] * row[w - 1] + wr[1] * row[w] + wr[2] * row[w + 1];
      } else {
        for (int kw = 0; kw < 3; ++kw) {
          int wwp = w + kw - 1;
          if (wwp >= 0 && wwp < 512) acc += wr[kw] * row[wwp];
        }
      }
    }
  }
  if (LEAKY) acc = acc > 0.f ? acc : 0.1f * acc;
  if (RES) acc += res[idx];
  out[idx] = acc;
}

// ---------------- grouped 1x1 qkv conv; Q -> qout (B,64,HW), K/V -> kvout (B,128,HW) --------
__global__ __launch_bounds__(256) void qkv1x1_k(const float* __restrict__ r,
                                                const float* __restrict__ wgt,
                                                const float* __restrict__ bias,
                                                float* __restrict__ qout,
                                                float* __restrict__ kvout) {
  int idx = blockIdx.x * 256 + threadIdx.x;  // over B*192*HW
  int p = idx & (HW - 1);
  int v = idx >> 17;          // b*192 + o, v in [0,384)
  int b = v >= 192 ? 1 : 0;
  int o = v - b * 192;        // uniform within block
  int g = o / 48;
  __shared__ float wsm[16];
  if (threadIdx.x < 16) wsm[threadIdx.x] = wgt[o * 16 + threadIdx.x];
  __syncthreads();
  const float* rb = r + ((size_t)(b * 64 + g * 16)) * HW + p;
  float acc = bias[o];
  for (int ci = 0; ci < 16; ++ci) acc += wsm[ci] * rb[(size_t)ci * HW];
  if (o < 64)
    qout[((size_t)(b * 64 + o)) * HW + p] = acc;
  else
    kvout[((size_t)(b * 128 + (o - 64))) * HW + p] = acc;
}

// ---------------- fused per-window attention ----------------
__global__ __launch_bounds__(256) void attn_fused_k(const float* __restrict__ qL,
                                                    const float* __restrict__ qR,
                                                    const float* __restrict__ kvL,
                                                    const float* __restrict__ kvR,
                                                    const float* __restrict__ dL,
                                                    const float* __restrict__ dR,
                                                    const float* __restrict__ xL,
                                                    const float* __restrict__ xR,
                                                    float* __restrict__ outL,
                                                    float* __restrict__ outR) {
  const int n = blockIdx.x;
  const int b = n >> 11;
  const int hb = (n >> 6) & 31;
  const int wb = n & 63;
  const int tid = threadIdx.x;

  __shared__ float lds[24720];
  float* sQl = lds;            // [j][c]  -> later V_r as [k][c]
  float* sQr = lds + 4096;     // [j][c]  -> later V_l as [k][c]
  float* sKr = lds + 8192;     // [c][k]
  float* sKl = lds + 12288;    // [c][k]
  float* sMr = lds + 16384;    // [j][k]
  float* sMl = lds + 20480;    // [j][k]
  float* sml = lds + 24576;    // 64 (means r, then m_left map)
  float* smr = lds + 24640;    // 64 (means l, then m_right map)

  const float* Qlb = qL + (size_t)b * 64 * HW;
  const float* Qrb = qR + (size_t)b * 64 * HW;
  const float* Klb = kvL + (size_t)b * 128 * HW;
  const float* Vlb = Klb + (size_t)64 * HW;
  const float* Krb = kvR + (size_t)b * 128 * HW;
  const float* Vrb = Krb + (size_t)64 * HW;
  const float* dLb = dL + (size_t)b * HW;
  const float* dRb = dR + (size_t)b * HW;

  // Q load: [j][c]
  for (int idx = tid; idx < 4096; idx += 256) {
    int c = idx >> 6, j = idx & 63;
    int hp = hb * 8 + (j >> 3), wp = wb * 8 + (j & 7);
    size_t off = (size_t)c * HW + hp * 512 + wp;
    sQl[j * 64 + c] = Qlb[off];
    sQr[j * 64 + c] = Qrb[off];
  }
  // K gather (layout-quirk patchify): [c2][k]
  for (int idx = tid; idx < 4096; idx += 256) {
    int c2 = idx >> 6, k = idx & 63;
    int s = hb * 4096 + (k >> 3) * 512 + wb * 8 + (k & 7);
    int hh = 4 * c2 + (s >> 15);
    int rem = s & 32767;
    int ww = rem >> 6, cc = rem & 63;
    int dpos = hh * 512 + ww;
    int iwr = ww - (int)dLb[dpos]; iwr = min(max(iwr, 0), 511);
    int iwl = ww + (int)dRb[dpos]; iwl = min(max(iwl, 0), 511);
    sKr[c2 * 64 + k] = Krb[(size_t)cc * HW + hh * 512 + iwr];
    sKl[c2 * 64 + k] = Klb[(size_t)cc * HW + hh * 512 + iwl];
  }
  __syncthreads();
  // per-hi mean over (c2, wi), 512 elems each
  {
    int grp = tid >> 5;  // hi
    int lane = tid & 31;
    float s1 = 0.f, s2 = 0.f;
    for (int e = lane; e < 512; e += 32) {
      int c2 = e >> 3, wi = e & 7;
      s1 += sKr[c2 * 64 + grp * 8 + wi];
      s2 += sKl[c2 * 64 + grp * 8 + wi];
    }
    for (int m = 16; m; m >>= 1) {
      s1 += __shfl_xor(s1, m, 32);
      s2 += __shfl_xor(s2, m, 32);
    }
    if (lane == 0) { sml[grp] = s1 * (1.f / 512.f); smr[grp] = s2 * (1.f / 512.f); }
  }
  __syncthreads();
  for (int idx = tid; idx < 4096; idx += 256) {
    int hi = (idx & 63) >> 3;
    sKr[idx] -= sml[hi];
    sKl[idx] -= smr[hi];
  }
  __syncthreads();
  // scores: S[j][k] = sum_c Q[j][c]*K[c][k], 4x4 micro-tiles
  {
    int j0 = (tid >> 4) * 4, k0 = (tid & 15) * 4;
    float aR[4][4] = {{0.f}}, aL[4][4] = {{0.f}};
    for (int c = 0; c < 64; ++c) {
      float ql[4], qr[4], kr[4], kl[4];
      for (int a = 0; a < 4; ++a) {
        ql[a] = sQl[(j0 + a) * 64 + c];
        qr[a] = sQr[(j0 + a) * 64 + c];
        kr[a] = sKr[c * 64 + k0 + a];
        kl[a] = sKl[c * 64 + k0 + a];
      }
      for (int a = 0; a < 4; ++a)
        for (int d = 0; d < 4; ++d) {
          aR[a][d] += ql[a] * kr[d];
          aL[a][d] += qr[a] * kl[d];
        }
    }
    for (int a = 0; a < 4; ++a)
      for (int d = 0; d < 4; ++d) {
        sMr[(j0 + a) * 64 + k0 + d] = aR[a][d];
        sMl[(j0 + a) * 64 + k0 + d] = aL[a][d];
      }
  }
  __syncthreads();
  // softmax per row
  if (tid < 64) {
    float* rowR = sMr + tid * 64;
    float* rowL = sMl + tid * 64;
    float mR = rowR[0], mL = rowL[0];
    for (int k = 1; k < 64; ++k) { mR = fmaxf(mR, rowR[k]); mL = fmaxf(mL, rowL[k]); }
    float sR = 0.f, sL = 0.f;
    for (int k = 0; k < 64; ++k) {
      float eR = expf(rowR[k] - mR);
      float eL = expf(rowL[k] - mL);
      rowR[k] = eR; rowL[k] = eL;
      sR += eR; sL += eL;
    }
    float rR = 1.f / sR, rL = 1.f / sL;
    for (int k = 0; k < 64; ++k) { rowR[k] *= rR; rowL[k] *= rL; }
  }
  __syncthreads();
  // V gather into sQl/sQr (Q dead): [k][c2]
  for (int idx = tid; idx < 4096; idx += 256) {
    int k2 = idx >> 6, c2 = idx & 63;
    int s = hb * 4096 + (k2 >> 3) * 512 + wb * 8 + (k2 & 7);
    int hh = 4 * c2 + (s >> 15);
    int rem = s & 32767;
    int ww = rem >> 6, cc = rem & 63;
    int dpos = hh * 512 + ww;
    int iwr = ww - (int)dLb[dpos]; iwr = min(max(iwr, 0), 511);
    int iwl = ww + (int)dRb[dpos]; iwl = min(max(iwl, 0), 511);
    sQl[k2 * 64 + c2] = Vrb[(size_t)cc * HW + hh * 512 + iwr];  // V_r_sel
    sQr[k2 * 64 + c2] = Vlb[(size_t)cc * HW + hh * 512 + iwl];  // V_l_sel
  }
  // m maps: m_left[j] = sum_k relax(Mr2l)[j,k]*Ml2r[k,j]
  if (tid < 64) {
    int j = tid;
    float accl = 0.f, accr = 0.f;
    for (int k = 0; k < 64; ++k) {
      float rxR = 0.f, rxL = 0.f;
      for (int i = -2; i <= 2; ++i) {
        int jj = j + i;
        if (jj >= 0 && jj < 64) {
          rxR += sMr[jj * 64 + k];
          rxL += sMl[jj * 64 + k];
        }
      }
      accl += rxR * sMl[k * 64 + j];
      accr += rxL * sMr[k * 64 + j];
    }
    sml[j] = tanhf(5.f * accl);
    smr[j] = tanhf(5.f * accr);
  }
  __syncthreads();
  // PV + blend + store: X[j][c] = sum_k M[j][k]*V[k][c]
  {
    int j0 = (tid >> 4) * 4, c0 = (tid & 15) * 4;
    float aL2[4][4] = {{0.f}}, aR2[4][4] = {{0.f}};
    for (int k = 0; k < 64; ++k) {
      float mr[4], ml_[4], vr[4], vl[4];
      for (int a = 0; a < 4; ++a) {
        mr[a] = sMr[(j0 + a) * 64 + k];
        ml_[a] = sMl[(j0 + a) * 64 + k];
      }
      for (int d = 0; d < 4; ++d) {
        vr[d] = sQl[k * 64 + c0 + d];
        vl[d] = sQr[k * 64 + c0 + d];
      }
      for (int a = 0; a < 4; ++a)
        for (int d = 0; d < 4; ++d) {
          aL2[a][d] += mr[a] * vr[d];
          aR2[a][d] += ml_[a] * vl[d];
        }
    }
    for (int a = 0; a < 4; ++a) {
      int j = j0 + a;
      int hp = hb * 8 + (j >> 3), wp = wb * 8 + (j & 7);
      float mlj = sml[j], mrj = smr[j];
      for (int d = 0; d < 4; ++d) {
        int c = c0 + d;
        size_t off = ((size_t)(b * 64 + c)) * HW + hp * 512 + wp;
        outL[off] = xL[off] * (1.f - mlj) + aL2[a][d] * mlj;
        outR[off] = xR[off] * (1.f - mrj) + aR2[a][d] * mrj;
      }
    }
  }
}

extern "C" void kernel_launch(void* const* d_in, const int* in_sizes, int n_in,
                              void* d_out, int out_size, void* d_ws, size_t ws_size,
                              hipStream_t stream) {
  const float* x_left = (const float*)d_in[0];
  const float* x_right = (const float*)d_in[1];
  const float* d_left = (const float*)d_in[2];
  const float* d_right = (const float*)d_in[3];
  const float* bn_gamma = (const float*)d_in[4];
  const float* bn_beta = (const float*)d_in[5];
  const float* rb_w1 = (const float*)d_in[6];
  const float* rb_b1 = (const float*)d_in[7];
  const float* rb_w2 = (const float*)d_in[8];
  const float* rb_b2 = (const float*)d_in[9];
  const float* qkv_w = (const float*)d_in[10];
  const float* qkv_b = (const float*)d_in[11];

  float* ws = (float*)d_ws;
  const size_t S = S_ELEMS;
  float* buf_y = ws;                 // S
  float* buf_t = ws + S;             // S
  float* buf_r = ws + 2 * S;         // S
  float* kvL = ws + 3 * S;           // 2S  (B,128,HW): K then V
  float* kvR = ws + 5 * S;           // 2S
  float* stats = ws + 7 * S;         // 256 floats

  float* out_left = (float*)d_out;       // also stages Q_left (B,64,HW)
  float* out_right = out_left + S;       // also stages Q_right

  for (int side = 0; side < 2; ++side) {
    const float* x = side ? x_right : x_left;
    float* kv = side ? kvR : kvL;
    float* q = side ? out_right : out_left;
    float* mu = stats + side * 128;
    float* rstd = mu + 64;
    bn_stats_k<<<64, 256, 0, stream>>>(x, mu, rstd);
    bn_apply_k<<<65536, 256, 0, stream>>>(x, buf_y, mu, rstd, bn_gamma, bn_beta);
    conv3x3g_k<true, false><<<65536, 256, 0, stream>>>(buf_y, rb_w1, rb_b1, nullptr, buf_t);
    conv3x3g_k<false, true><<<65536, 256, 0, stream>>>(buf_t, rb_w2, rb_b2, buf_y, buf_r);
    qkv1x1_k<<<196608, 256, 0, stream>>>(buf_r, qkv_w, qkv_b, q, kv);
  }
  attn_fused_k<<<4096, 256, 0, stream>>>(out_left, out_right, kvL, kvR,
                                         d_left, d_right, x_left, x_right,
                                         out_left, out_right);
}

// Round 2
// 1534.174 us; speedup vs baseline: 3.4034x; 3.4034x over previous
//
#include <hip/hip_runtime.h>
#include <cstdint>

#define HW 131072        // H*W
#define S_ELEMS 16777216 // B*C*H*W

// ---------------- BN stats (both sides): emit scale/shift ----------------
__global__ __launch_bounds__(256) void bn_stats_k(const float* __restrict__ xL,
                                                  const float* __restrict__ xR,
                                                  const float* __restrict__ gamma,
                                                  const float* __restrict__ beta,
                                                  float* __restrict__ stats) {
  int side = blockIdx.x >> 6;
  int c = blockIdx.x & 63;
  const float* x = side ? xR : xL;
  float s1 = 0.f, s2 = 0.f;
  for (int bb = 0; bb < 2; ++bb) {
    const float4* p = (const float4*)(x + ((size_t)(bb * 64 + c)) * HW);
    for (int i = threadIdx.x; i < HW / 4; i += 256) {
      float4 v = p[i];
      s1 += v.x + v.y + v.z + v.w;
      s2 += v.x * v.x + v.y * v.y + v.z * v.z + v.w * v.w;
    }
  }
  for (int m = 32; m; m >>= 1) {
    s1 += __shfl_xor(s1, m, 64);
    s2 += __shfl_xor(s2, m, 64);
  }
  __shared__ float r1[4], r2[4];
  int wv = threadIdx.x >> 6;
  if ((threadIdx.x & 63) == 0) { r1[wv] = s1; r2[wv] = s2; }
  __syncthreads();
  if (threadIdx.x == 0) {
    float t1 = r1[0] + r1[1] + r1[2] + r1[3];
    float t2 = r2[0] + r2[1] + r2[2] + r2[3];
    float mu = t1 / 262144.f;
    float var = t2 / 262144.f - mu * mu;
    float rs = rsqrtf(var + 1e-5f);
    float sc = rs * gamma[c];
    stats[side * 128 + c] = sc;
    stats[side * 128 + 64 + c] = beta[c] - mu * sc;
  }
}

// ---------------- tiled grouped 3x3 conv ----------------
// block: (b, g, 8-row x 64-col tile); computes all 16 output channels of group.
// BNIN: apply y=x*sc+sh while staging input. RES: add bn(xres) in epilogue.
template <bool BNIN, bool LEAKY, bool RES>
__global__ __launch_bounds__(256) void conv3x3_t(const float* __restrict__ in,
                                                 const float* __restrict__ wgt,
                                                 const float* __restrict__ bias,
                                                 const float* __restrict__ ss,
                                                 const float* __restrict__ xres,
                                                 float* __restrict__ out) {
  __shared__ float sIn[16 * 10 * 68];
  __shared__ float sW[16 * 16 * 3 * 4];  // [o][ci][kh] -> float4 {w0,w1,w2,pad}
  __shared__ float sSc[16], sSh[16];
  int bid = blockIdx.x;
  int tw = bid & 7, th = (bid >> 3) & 31, g = (bid >> 8) & 3, b = bid >> 10;
  int tid = threadIdx.x;
  for (int e = tid; e < 2304; e += 256) {
    int o = e / 144, rem = e - o * 144, ci = rem / 9, k = rem - ci * 9;
    sW[((o * 16 + ci) * 3 + k / 3) * 4 + k % 3] = wgt[(g * 16 + o) * 144 + rem];
  }
  if ((BNIN || RES) && tid < 16) { sSc[tid] = ss[g * 16 + tid]; sSh[tid] = ss[64 + g * 16 + tid]; }
  int h0 = th * 8 - 1, w0 = tw * 64 - 1;
  const float* inb = in + ((size_t)(b * 64 + g * 16)) * HW;
  for (int e = tid; e < 10560; e += 256) {
    int ci = e / 660, rem = e - ci * 660, r = rem / 66, c = rem - r * 66;
    int h = h0 + r, w = w0 + c;
    float v = 0.f;
    if ((unsigned)h < 256u && (unsigned)w < 512u) {
      v = inb[(size_t)ci * HW + h * 512 + w];
      if (BNIN) v = v * sSc[ci] + sSh[ci];
    }
    sIn[ci * 680 + r * 68 + c] = v;
  }
  __syncthreads();
  int oh = tid >> 7;  // 0..1 : output-channel half
  int pxi = tid & 127;
  int row = pxi >> 4, col = (pxi & 15) * 4;
  float acc[8][4];
#pragma unroll
  for (int o = 0; o < 8; ++o) {
    float bz = bias[g * 16 + oh * 8 + o];
#pragma unroll
    for (int p = 0; p < 4; ++p) acc[o][p] = bz;
  }
  for (int ci = 0; ci < 16; ++ci) {
    float v[3][6];
    const float* base = sIn + ci * 680 + row * 68 + col;
#pragma unroll
    for (int kh = 0; kh < 3; ++kh) {
      float4 a4 = *(const float4*)(base + kh * 68);
      float2 a2 = *(const float2*)(base + kh * 68 + 4);
      v[kh][0] = a4.x; v[kh][1] = a4.y; v[kh][2] = a4.z; v[kh][3] = a4.w;
      v[kh][4] = a2.x; v[kh][5] = a2.y;
    }
    const float4* wb = (const float4*)sW + ((oh * 8) * 16 + ci) * 3;
#pragma unroll
    for (int o = 0; o < 8; ++o) {
      const float4* wo = wb + o * 48;
#pragma unroll
      for (int kh = 0; kh < 3; ++kh) {
        float4 wv = wo[kh];
#pragma unroll
        for (int p = 0; p < 4; ++p)
          acc[o][p] += wv.x * v[kh][p] + wv.y * v[kh][p + 1] + wv.z * v[kh][p + 2];
      }
    }
  }
  int h = th * 8 + row, wcol = tw * 64 + col;
#pragma unroll
  for (int o = 0; o < 8; ++o) {
    int cg = g * 16 + oh * 8 + o;
    size_t off = ((size_t)(b * 64 + cg)) * HW + h * 512 + wcol;
    float4 r4;
    float* rp = (float*)&r4;
    if (RES) {
      float4 x4 = *(const float4*)(xres + off);
      float sc = sSc[oh * 8 + o], sh = sSh[oh * 8 + o];
      float xr0 = x4.x * sc + sh, xr1 = x4.y * sc + sh, xr2 = x4.z * sc + sh, xr3 = x4.w * sc + sh;
      float a0 = acc[o][0], a1 = acc[o][1], a2 = acc[o][2], a3 = acc[o][3];
      if (LEAKY) { a0 = a0 > 0 ? a0 : 0.1f * a0; a1 = a1 > 0 ? a1 : 0.1f * a1; a2 = a2 > 0 ? a2 : 0.1f * a2; a3 = a3 > 0 ? a3 : 0.1f * a3; }
      rp[0] = a0 + xr0; rp[1] = a1 + xr1; rp[2] = a2 + xr2; rp[3] = a3 + xr3;
    } else {
#pragma unroll
      for (int p = 0; p < 4; ++p) {
        float a = acc[o][p];
        if (LEAKY) a = a > 0.f ? a : 0.1f * a;
        rp[p] = a;
      }
    }
    *(float4*)(out + off) = r4;
  }
}

// ---------------- 1x1 qkv conv: thread = pixel, all 192 outputs ----------------
__global__ __launch_bounds__(256) void qkv_k(const float* __restrict__ r,
                                             const float* __restrict__ wgt,
                                             const float* __restrict__ bias,
                                             float* __restrict__ qout,
                                             float* __restrict__ kvout) {
  __shared__ float sW[3072];
  __shared__ float sB[192];
  int tid = threadIdx.x;
  for (int e = tid; e < 3072; e += 256) sW[e] = wgt[e];
  if (tid < 192) sB[tid] = bias[tid];
  __syncthreads();
  int idx = blockIdx.x * 256 + tid;  // over B*HW
  int p = idx & (HW - 1);
  int b = idx >> 17;
  const float* rb = r + (size_t)b * 64 * HW + p;
  float* qb = qout + (size_t)b * 64 * HW + p;
  float* kvb = kvout + (size_t)b * 128 * HW + p;
  for (int g = 0; g < 4; ++g) {
    float in[16];
#pragma unroll
    for (int ci = 0; ci < 16; ++ci) in[ci] = rb[(size_t)(g * 16 + ci) * HW];
    for (int oo = 0; oo < 48; ++oo) {
      int o = g * 48 + oo;
      const float4* w4 = (const float4*)(sW + o * 16);
      float acc = sB[o];
#pragma unroll
      for (int q = 0; q < 4; ++q) {
        float4 wv = w4[q];
        acc += wv.x * in[q * 4] + wv.y * in[q * 4 + 1] + wv.z * in[q * 4 + 2] + wv.w * in[q * 4 + 3];
      }
      if (o < 64) qb[(size_t)o * HW] = acc;
      else kvb[(size_t)(o - 64) * HW] = acc;
    }
  }
}

// ---------------- fused per-window attention (LDS-reuse, pad-65) ----------------
__global__ __launch_bounds__(256) void attn_fused_k(const float* __restrict__ qL,
                                                    const float* __restrict__ qR,
                                                    const float* __restrict__ kvL,
                                                    const float* __restrict__ kvR,
                                                    const float* __restrict__ dL,
                                                    const float* __restrict__ dR,
                                                    const float* __restrict__ xL,
                                                    const float* __restrict__ xR,
                                                    float* __restrict__ outL,
                                                    float* __restrict__ outR) {
  const int n = blockIdx.x;
  const int b = n >> 11;
  const int hb = (n >> 6) & 31;
  const int wb = n & 63;
  const int tid = threadIdx.x;

  // A: Ql[j][c] -> Mr2l[j][k];  B: Qr[j][c] -> Ml2r[j][k]
  // C: Kr[c2][k] -> Vr_sel[k][c];  D: Kl[c2][k] -> Vl_sel[k][c]
  __shared__ float A[4160], B[4160], C[4160], D[4160];
  __shared__ float mA[64], mB[64];  // means, then m_left / m_right maps

  const float* Qlb = qL + (size_t)b * 64 * HW;
  const float* Qrb = qR + (size_t)b * 64 * HW;
  const float* Klb = kvL + (size_t)b * 128 * HW;
  const float* Vlb = Klb + (size_t)64 * HW;
  const float* Krb = kvR + (size_t)b * 128 * HW;
  const float* Vrb = Krb + (size_t)64 * HW;
  const float* dLb = dL + (size_t)b * HW;
  const float* dRb = dR + (size_t)b * HW;

  // Phase 1: Q load + K gather
  for (int idx = tid; idx < 4096; idx += 256) {
    int c = idx >> 6, j = idx & 63;
    int hp = hb * 8 + (j >> 3), wp = wb * 8 + (j & 7);
    size_t off = (size_t)c * HW + hp * 512 + wp;
    A[j * 65 + c] = Qlb[off];
    B[j * 65 + c] = Qrb[off];
  }
  for (int idx = tid; idx < 4096; idx += 256) {
    int c2 = idx >> 6, k = idx & 63;
    int s = hb * 4096 + (k >> 3) * 512 + wb * 8 + (k & 7);
    int hh = 4 * c2 + (s >> 15);
    int rem = s & 32767;
    int ww = rem >> 6, cc = rem & 63;
    int dpos = hh * 512 + ww;
    int iwr = ww - (int)dLb[dpos]; iwr = min(max(iwr, 0), 511);
    int iwl = ww + (int)dRb[dpos]; iwl = min(max(iwl, 0), 511);
    C[c2 * 65 + k] = Krb[(size_t)cc * HW + hh * 512 + iwr];
    D[c2 * 65 + k] = Klb[(size_t)cc * HW + hh * 512 + iwl];
  }
  __syncthreads();
  // K means per hi over (c2, wi)
  {
    int grp = tid >> 5;  // hi
    int lane = tid & 31;
    float s1 = 0.f, s2 = 0.f;
    for (int e = lane; e < 512; e += 32) {
      int c2 = e >> 3, wi = e & 7;
      s1 += C[c2 * 65 + grp * 8 + wi];
      s2 += D[c2 * 65 + grp * 8 + wi];
    }
    for (int m = 16; m; m >>= 1) {
      s1 += __shfl_xor(s1, m, 32);
      s2 += __shfl_xor(s2, m, 32);
    }
    if (lane == 0) { mA[grp] = s1 * (1.f / 512.f); mB[grp] = s2 * (1.f / 512.f); }
  }
  __syncthreads();
  for (int idx = tid; idx < 4096; idx += 256) {
    int c2 = idx >> 6, k = idx & 63;
    int hi = k >> 3;
    C[c2 * 65 + k] -= mA[hi];
    D[c2 * 65 + k] -= mB[hi];
  }
  __syncthreads();
  // Phase 2: scores in registers. rows j0+16a, cols k0+d
  const int j0 = tid & 15;
  const int k0 = (tid >> 4) * 4;
  float aR[4][4] = {{0.f}}, aL[4][4] = {{0.f}};
  for (int c = 0; c < 64; ++c) {
    float ql[4], qr[4], kr[4], kl[4];
#pragma unroll
    for (int a = 0; a < 4; ++a) { ql[a] = A[(j0 + 16 * a) * 65 + c]; qr[a] = B[(j0 + 16 * a) * 65 + c]; }
#pragma unroll
    for (int d = 0; d < 4; ++d) { kr[d] = C[c * 65 + k0 + d]; kl[d] = D[c * 65 + k0 + d]; }
#pragma unroll
    for (int a = 0; a < 4; ++a)
#pragma unroll
      for (int d = 0; d < 4; ++d) {
        aR[a][d] += ql[a] * kr[d];
        aL[a][d] += qr[a] * kl[d];
      }
  }
  __syncthreads();
  // Phase 3: write scores into A/B; gather V into C/D
#pragma unroll
  for (int a = 0; a < 4; ++a)
#pragma unroll
    for (int d = 0; d < 4; ++d) {
      A[(j0 + 16 * a) * 65 + k0 + d] = aR[a][d];
      B[(j0 + 16 * a) * 65 + k0 + d] = aL[a][d];
    }
  for (int idx = tid; idx < 4096; idx += 256) {
    int k2 = idx >> 6, c2 = idx & 63;
    int s = hb * 4096 + (k2 >> 3) * 512 + wb * 8 + (k2 & 7);
    int hh = 4 * c2 + (s >> 15);
    int rem = s & 32767;
    int ww = rem >> 6, cc = rem & 63;
    int dpos = hh * 512 + ww;
    int iwr = ww - (int)dLb[dpos]; iwr = min(max(iwr, 0), 511);
    int iwl = ww + (int)dRb[dpos]; iwl = min(max(iwl, 0), 511);
    C[k2 * 65 + c2] = Vrb[(size_t)cc * HW + hh * 512 + iwr];
    D[k2 * 65 + c2] = Vlb[(size_t)cc * HW + hh * 512 + iwl];
  }
  __syncthreads();
  // Phase 4: softmax, one row per thread (128 rows)
  if (tid < 128) {
    float* row = (tid < 64 ? A : B) + (tid & 63) * 65;
    float mx = row[0];
    for (int k = 1; k < 64; ++k) mx = fmaxf(mx, row[k]);
    float s = 0.f;
    for (int k = 0; k < 64; ++k) {
      float e = __expf(row[k] - mx);
      row[k] = e;
      s += e;
    }
    float rs = 1.f / s;
    for (int k = 0; k < 64; ++k) row[k] *= rs;
  }
  __syncthreads();
  // Phase 5: m maps (128 threads)
  if (tid < 128) {
    int j = tid & 63;
    float acc = 0.f;
    if (tid < 64) {
      for (int k = 0; k < 64; ++k) {
        float rx = 0.f;
#pragma unroll
        for (int i = -2; i <= 2; ++i) {
          int jj = j + i;
          if (jj >= 0 && jj < 64) rx += A[jj * 65 + k];
        }
        acc += rx * B[k * 65 + j];
      }
      mA[j] = tanhf(5.f * acc);  // m_left
    } else {
      for (int k = 0; k < 64; ++k) {
        float rx = 0.f;
#pragma unroll
        for (int i = -2; i <= 2; ++i) {
          int jj = j + i;
          if (jj >= 0 && jj < 64) rx += B[jj * 65 + k];
        }
        acc += rx * A[k * 65 + j];
      }
      mB[j] = tanhf(5.f * acc);  // m_right
    }
  }
  __syncthreads();
  // Phase 6: PV + blend + store. rows j0+16a, channels c0+d
  const int c0 = k0;
  float oL[4][4] = {{0.f}}, oR[4][4] = {{0.f}};
  for (int k = 0; k < 64; ++k) {
    float mr[4], ml[4], vr[4], vl[4];
#pragma unroll
    for (int a = 0; a < 4; ++a) { mr[a] = A[(j0 + 16 * a) * 65 + k]; ml[a] = B[(j0 + 16 * a) * 65 + k]; }
#pragma unroll
    for (int d = 0; d < 4; ++d) { vr[d] = C[k * 65 + c0 + d]; vl[d] = D[k * 65 + c0 + d]; }
#pragma unroll
    for (int a = 0; a < 4; ++a)
#pragma unroll
      for (int d = 0; d < 4; ++d) {
        oL[a][d] += mr[a] * vr[d];
        oR[a][d] += ml[a] * vl[d];
      }
  }
#pragma unroll
  for (int a = 0; a < 4; ++a) {
    int j = j0 + 16 * a;
    int hp = hb * 8 + (j >> 3), wp = wb * 8 + (j & 7);
    float mlj = mA[j], mrj = mB[j];
#pragma unroll
    for (int d = 0; d < 4; ++d) {
      int c = c0 + d;
      size_t off = ((size_t)(b * 64 + c)) * HW + hp * 512 + wp;
      outL[off] = xL[off] * (1.f - mlj) + oL[a][d] * mlj;
      outR[off] = xR[off] * (1.f - mrj) + oR[a][d] * mrj;
    }
  }
}

extern "C" void kernel_launch(void* const* d_in, const int* in_sizes, int n_in,
                              void* d_out, int out_size, void* d_ws, size_t ws_size,
                              hipStream_t stream) {
  const float* x_left = (const float*)d_in[0];
  const float* x_right = (const float*)d_in[1];
  const float* d_left = (const float*)d_in[2];
  const float* d_right = (const float*)d_in[3];
  const float* bn_gamma = (const float*)d_in[4];
  const float* bn_beta = (const float*)d_in[5];
  const float* rb_w1 = (const float*)d_in[6];
  const float* rb_b1 = (const float*)d_in[7];
  const float* rb_w2 = (const float*)d_in[8];
  const float* rb_b2 = (const float*)d_in[9];
  const float* qkv_w = (const float*)d_in[10];
  const float* qkv_b = (const float*)d_in[11];

  float* ws = (float*)d_ws;
  const size_t S = S_ELEMS;
  float* buf_t = ws;             // S
  float* buf_r = ws + S;         // S
  float* kvL = ws + 2 * S;       // 2S (B,128,HW): K then V
  float* kvR = ws + 4 * S;       // 2S
  float* stats = ws + 6 * S;     // 256 floats (side-major: scale[64], shift[64])

  float* out_left = (float*)d_out;   // stages Q_left
  float* out_right = out_left + S;   // stages Q_right

  bn_stats_k<<<128, 256, 0, stream>>>(x_left, x_right, bn_gamma, bn_beta, stats);

  for (int side = 0; side < 2; ++side) {
    const float* x = side ? x_right : x_left;
    float* kv = side ? kvR : kvL;
    float* q = side ? out_right : out_left;
    const float* ss = stats + side * 128;
    conv3x3_t<true, true, false><<<2048, 256, 0, stream>>>(x, rb_w1, rb_b1, ss, nullptr, buf_t);
    conv3x3_t<false, false, true><<<2048, 256, 0, stream>>>(buf_t, rb_w2, rb_b2, ss, x, buf_r);
    qkv_k<<<1024, 256, 0, stream>>>(buf_r, qkv_w, qkv_b, q, kv);
  }
  attn_fused_k<<<4096, 256, 0, stream>>>(out_left, out_right, kvL, kvR,
                                         d_left, d_right, x_left, x_right,
                                         out_left, out_right);
}